// Round 5
// baseline (2012.749 us; speedup 1.0000x reference)
//
#include <hip/hip_runtime.h>
#include <stdint.h>

#define NODES 50000
#define EDGES 800000
#define EMB   256
#define MPAD  50048   // 391*128
#define BNEPS 1e-5f

typedef unsigned short u16;
typedef unsigned int   u32;
typedef __attribute__((ext_vector_type(8))) short bf16x8;
typedef __attribute__((ext_vector_type(4))) float f32x4;

__device__ __forceinline__ float bf2f(u16 v){
  union { u32 u; float f; } t; t.u = ((u32)v) << 16; return t.f;
}
__device__ __forceinline__ u16 f2bf(float f){
  union { float f; u32 u; } t; t.f = f;
  return (u16)((t.u + 0x7fffu + ((t.u >> 16) & 1u)) >> 16);
}
// split f32 into hi+lo bf16 (a - bf2f(hi) is exact: Sterbenz)
__device__ __forceinline__ void split2(float a, u16& hi, u16& lo){
  hi = f2bf(a);
  lo = f2bf(a - bf2f(hi));
}
__device__ __forceinline__ void gload16(const void* g, void* l){
  __builtin_amdgcn_global_load_lds((const __attribute__((address_space(1))) void*)g,
                                   (__attribute__((address_space(3))) void*)l, 16, 0, 0);
}

// ---------------- setup kernels ----------------

__global__ void k_w1t(const float* __restrict__ W1, u16* __restrict__ Whi,
                      u16* __restrict__ Wlo){
  int i = blockIdx.x * 256 + threadIdx.x;          // 5*512*256, dst layout [l][n][k]
  if (i >= 5*512*256) return;
  int k = i & 255, n = (i >> 8) & 511, l = i >> 17;
  float v = W1[((size_t)l << 17) + ((size_t)k << 9) + n];
  u16 h_, l_; split2(v, h_, l_);
  Whi[i] = h_; Wlo[i] = l_;
}
__global__ void k_w2t(const float* __restrict__ W2, u16* __restrict__ Whi,
                      u16* __restrict__ Wlo){
  int i = blockIdx.x * 256 + threadIdx.x;          // 5*256*512, dst layout [l][n][k]
  if (i >= 5*256*512) return;
  int k = i & 511, n = (i >> 9) & 255, l = i >> 17;
  float v = W2[((size_t)l << 17) + ((size_t)k << 8) + n];
  u16 h_, l_; split2(v, h_, l_);
  Whi[i] = h_; Wlo[i] = l_;
}

__global__ void k_ebond(const float* __restrict__ bemb, float* __restrict__ eb){
  int l = blockIdx.x / 216, p = blockIdx.x % 216;
  int a0 = p % 6, a1 = (p / 6) % 6, a2 = p / 36;
  int d0 = threadIdx.x * 4;
  const float* b = bemb + (size_t)l * 3 * 6 * 256;
  float4 v0 = *(const float4*)(b + (0*6 + a0)*256 + d0);
  float4 v1 = *(const float4*)(b + (1*6 + a1)*256 + d0);
  float4 v2 = *(const float4*)(b + (2*6 + a2)*256 + d0);
  float4 o; o.x = v0.x+v1.x+v2.x; o.y = v0.y+v1.y+v2.y;
  o.z = v0.z+v1.z+v2.z; o.w = v0.w+v1.w+v2.w;
  *(float4*)(eb + (((size_t)l*216 + p) << 8) + d0) = o;
}

__global__ void k_atom(const int* __restrict__ x, const float* __restrict__ aemb,
                       float* __restrict__ h){
  int n = blockIdx.x * 4 + (threadIdx.x >> 6);
  int lane = threadIdx.x & 63;
  if (n >= NODES) return;
  int d0 = lane * 4;
  float a0=0.f, a1=0.f, a2=0.f, a3=0.f;
#pragma unroll
  for (int f = 0; f < 9; ++f){
    int v = x[n*9 + f];
    float4 e = *(const float4*)(aemb + (((size_t)f*120 + v) << 8) + d0);
    a0 += e.x; a1 += e.y; a2 += e.z; a3 += e.w;
  }
  float4 o; o.x=a0; o.y=a1; o.z=a2; o.w=a3;
  *(float4*)(h + (size_t)n*EMB + d0) = o;
}

// ---------------- CSR build ----------------

__global__ void k_hist(const int* __restrict__ dst, int* __restrict__ counts){
  int e = blockIdx.x * 256 + threadIdx.x;
  if (e < EDGES) atomicAdd(&counts[dst[e]], 1);
}

__global__ void k_scan(const int* __restrict__ counts, int* __restrict__ rs,
                       int* __restrict__ fill){
  __shared__ int part[1024];
  int t = threadIdx.x;
  const int CH = 49;                                // 1024*49 >= 50000
  int begin = t * CH;
  int end = begin + CH; if (end > NODES) end = NODES;
  if (begin > NODES) begin = NODES;
  int s = 0;
  for (int i = begin; i < end; ++i) s += counts[i];
  part[t] = s; __syncthreads();
  for (int off = 1; off < 1024; off <<= 1){
    int v = (t >= off) ? part[t - off] : 0;
    __syncthreads();
    part[t] += v;
    __syncthreads();
  }
  int run = part[t] - s;                            // exclusive prefix
  for (int i = begin; i < end; ++i){
    rs[i] = run; fill[i] = run; run += counts[i];
  }
  if (t == 1023) rs[NODES] = part[1023];
}

__global__ void k_scatter(const int* __restrict__ src, const int* __restrict__ dst,
                          const int* __restrict__ ea, int* __restrict__ fill,
                          int* __restrict__ csrc, int* __restrict__ cattr){
  int e = blockIdx.x * 256 + threadIdx.x;
  if (e >= EDGES) return;
  int d = dst[e];
  int p = atomicAdd(&fill[d], 1);
  csrc[p]  = src[e];
  cattr[p] = ea[e*3+0] + 6*ea[e*3+1] + 36*ea[e*3+2];
}

// ---------------- per-layer kernels ----------------

__global__ void k_gather(const float* __restrict__ h, const float* __restrict__ ebl,
                         const int* __restrict__ rs, const int* __restrict__ csrc,
                         const int* __restrict__ cattr, const float* __restrict__ epsv,
                         int layer, u16* __restrict__ zhi, u16* __restrict__ zlo){
  int n = blockIdx.x * 4 + (threadIdx.x >> 6);
  int lane = threadIdx.x & 63;
  int d0 = lane * 4;
  if (n >= MPAD) return;
  size_t zoff = (size_t)n * EMB + d0;
  if (n >= NODES){
    ushort4 zz = make_ushort4(0,0,0,0);
    *(ushort4*)(zhi + zoff) = zz; *(ushort4*)(zlo + zoff) = zz;
    return;
  }
  float ep = 1.0f + epsv[layer];
  float4 hv = *(const float4*)(h + (size_t)n*EMB + d0);
  float a0 = ep*hv.x, a1 = ep*hv.y, a2 = ep*hv.z, a3 = ep*hv.w;
  int i1 = rs[n+1];
  for (int i = rs[n]; i < i1; ++i){
    int s  = csrc[i];
    int pa = cattr[i];
    float4 hs = *(const float4*)(h + (size_t)s*EMB + d0);
    float4 e4 = *(const float4*)(ebl + ((size_t)pa << 8) + d0);
    a0 += fmaxf(hs.x + e4.x, 0.f);
    a1 += fmaxf(hs.y + e4.y, 0.f);
    a2 += fmaxf(hs.z + e4.z, 0.f);
    a3 += fmaxf(hs.w + e4.w, 0.f);
  }
  ushort4 oh, ol;
  split2(a0, oh.x, ol.x); split2(a1, oh.y, ol.y);
  split2(a2, oh.z, ol.z); split2(a3, oh.w, ol.w);
  *(ushort4*)(zhi + zoff) = oh; *(ushort4*)(zlo + zoff) = ol;
}

// A [M x K] hi/lo bf16 row-major, Bt [NCOL x K] hi/lo bf16 (pre-transposed weights).
// C [M x NCOL] hi/lo bf16 pre-BN; column sum/sumsq accumulated via f32 atomics.
// acc = (Ah+Al)*(Bh+Bl) ~ Ah*Bh + Ah*Bl + Al*Bh  (3 MFMAs; lo*lo ~2^-18, dropped)
template<int K, int NCOL>
__global__ __launch_bounds__(256)
void k_gemm(const u16* __restrict__ Ah, const u16* __restrict__ Al,
            const u16* __restrict__ Bh, const u16* __restrict__ Bl,
            u16* __restrict__ Chi, u16* __restrict__ Clo,
            float* __restrict__ csum, float* __restrict__ csq){
  __shared__ __align__(16) u16 AsH[128*64];
  __shared__ __align__(16) u16 AsL[128*64];
  __shared__ __align__(16) u16 BsH[128*64];
  __shared__ __align__(16) u16 BsL[128*64];
  const int tid  = threadIdx.x;
  const int lane = tid & 63;
  const int wid  = tid >> 6;
  const int bm0 = blockIdx.x * 128;
  const int bn0 = blockIdx.y * 128;
  const int wm = (wid >> 1) * 64;
  const int wn = (wid & 1) * 64;

  f32x4 acc[4][4];
#pragma unroll
  for (int m = 0; m < 4; ++m)
#pragma unroll
    for (int n = 0; n < 4; ++n) acc[m][n] = (f32x4){0.f,0.f,0.f,0.f};

  for (int kt = 0; kt < K/64; ++kt){
    __syncthreads();
#pragma unroll
    for (int it = 0; it < 4; ++it){
      int tix = tid + it*256;
      int r = tix >> 3;
      int c = tix & 7;
      int sc = c ^ (r & 7);          // pre-swizzled global source, linear LDS dest
      size_t ga = (size_t)(bm0 + r)*K + kt*64 + sc*8;
      size_t gb = (size_t)(bn0 + r)*K + kt*64 + sc*8;
      gload16(Ah + ga, (char*)AsH + tix*16);
      gload16(Al + ga, (char*)AsL + tix*16);
      gload16(Bh + gb, (char*)BsH + tix*16);
      gload16(Bl + gb, (char*)BsL + tix*16);
    }
    __syncthreads();
#pragma unroll
    for (int kk = 0; kk < 2; ++kk){
      bf16x8 afh[4], afl[4], bfh[4], bfl[4];
#pragma unroll
      for (int m = 0; m < 4; ++m){
        int row = wm + m*16 + (lane & 15);
        int phys = (kk*4 + (lane >> 4)) ^ (row & 7);
        afh[m] = *(const bf16x8*)((const char*)AsH + row*128 + phys*16);
        afl[m] = *(const bf16x8*)((const char*)AsL + row*128 + phys*16);
      }
#pragma unroll
      for (int n = 0; n < 4; ++n){
        int row = wn + n*16 + (lane & 15);
        int phys = (kk*4 + (lane >> 4)) ^ (row & 7);
        bfh[n] = *(const bf16x8*)((const char*)BsH + row*128 + phys*16);
        bfl[n] = *(const bf16x8*)((const char*)BsL + row*128 + phys*16);
      }
#pragma unroll
      for (int m = 0; m < 4; ++m)
#pragma unroll
        for (int n = 0; n < 4; ++n){
          acc[m][n] = __builtin_amdgcn_mfma_f32_16x16x32_bf16(afl[m], bfh[n], acc[m][n], 0, 0, 0);
          acc[m][n] = __builtin_amdgcn_mfma_f32_16x16x32_bf16(afh[m], bfl[n], acc[m][n], 0, 0, 0);
          acc[m][n] = __builtin_amdgcn_mfma_f32_16x16x32_bf16(afh[m], bfh[n], acc[m][n], 0, 0, 0);
        }
    }
  }

  const int r0 = (lane >> 4) * 4;
  const int cc = lane & 15;
#pragma unroll
  for (int m = 0; m < 4; ++m)
#pragma unroll
    for (int n = 0; n < 4; ++n)
#pragma unroll
      for (int j = 0; j < 4; ++j){
        int row = bm0 + wm + m*16 + r0 + j;
        int col = bn0 + wn + n*16 + cc;
        u16 h_, l_; split2(acc[m][n][j], h_, l_);
        Chi[(size_t)row*NCOL + col] = h_;
        Clo[(size_t)row*NCOL + col] = l_;
      }
#pragma unroll
  for (int n = 0; n < 4; ++n){
    float s = 0.f, q = 0.f;
#pragma unroll
    for (int m = 0; m < 4; ++m)
#pragma unroll
      for (int j = 0; j < 4; ++j){ float v = acc[m][n][j]; s += v; q += v*v; }
    s += __shfl_xor(s, 16); q += __shfl_xor(q, 16);
    s += __shfl_xor(s, 32); q += __shfl_xor(q, 32);
    if (lane < 16){
      atomicAdd(csum + bn0 + wn + n*16 + cc, s);
      atomicAdd(csq  + bn0 + wn + n*16 + cc, q);
    }
  }
}

__global__ void k_finalize(const float* __restrict__ sum, const float* __restrict__ sumsq,
                           const float* __restrict__ g, const float* __restrict__ be,
                           float* __restrict__ scale, float* __restrict__ shift, int nc){
  int c = blockIdx.x * 256 + threadIdx.x;
  if (c >= nc) return;
  float m = sum[c] * (1.0f / NODES);
  float v = sumsq[c] * (1.0f / NODES) - m*m;
  float sc = rsqrtf(v + BNEPS) * g[c];
  scale[c] = sc;
  shift[c] = be[c] - m*sc;
}

__global__ void k_apply1(u16* __restrict__ hhi, u16* __restrict__ hlo,
                         const float* __restrict__ scale, const float* __restrict__ shift){
  int idx = blockIdx.x * 256 + threadIdx.x;       // 8 elems each, MPAD*512 total
  int row = idx >> 6;
  int c0  = (idx & 63) * 8;
  size_t off = (size_t)row * 512 + c0;
  if (row >= NODES){
    ushort4 zz = make_ushort4(0,0,0,0);
    *(ushort4*)(hhi + off) = zz; *(ushort4*)(hhi + off + 4) = zz;
    *(ushort4*)(hlo + off) = zz; *(ushort4*)(hlo + off + 4) = zz;
    return;
  }
  ushort4 h0 = *(const ushort4*)(hhi + off);
  ushort4 h1 = *(const ushort4*)(hhi + off + 4);
  ushort4 l0 = *(const ushort4*)(hlo + off);
  ushort4 l1 = *(const ushort4*)(hlo + off + 4);
  float4 sA = *(const float4*)(scale + c0), sB = *(const float4*)(scale + c0 + 4);
  float4 tA = *(const float4*)(shift + c0), tB = *(const float4*)(shift + c0 + 4);
  float r0 = fmaxf((bf2f(h0.x)+bf2f(l0.x))*sA.x + tA.x, 0.f);
  float r1 = fmaxf((bf2f(h0.y)+bf2f(l0.y))*sA.y + tA.y, 0.f);
  float r2 = fmaxf((bf2f(h0.z)+bf2f(l0.z))*sA.z + tA.z, 0.f);
  float r3 = fmaxf((bf2f(h0.w)+bf2f(l0.w))*sA.w + tA.w, 0.f);
  float r4 = fmaxf((bf2f(h1.x)+bf2f(l1.x))*sB.x + tB.x, 0.f);
  float r5 = fmaxf((bf2f(h1.y)+bf2f(l1.y))*sB.y + tB.y, 0.f);
  float r6 = fmaxf((bf2f(h1.z)+bf2f(l1.z))*sB.z + tB.z, 0.f);
  float r7 = fmaxf((bf2f(h1.w)+bf2f(l1.w))*sB.w + tB.w, 0.f);
  ushort4 oh0, ol0, oh1, ol1;
  split2(r0, oh0.x, ol0.x); split2(r1, oh0.y, ol0.y);
  split2(r2, oh0.z, ol0.z); split2(r3, oh0.w, ol0.w);
  split2(r4, oh1.x, ol1.x); split2(r5, oh1.y, ol1.y);
  split2(r6, oh1.z, ol1.z); split2(r7, oh1.w, ol1.w);
  *(ushort4*)(hhi + off) = oh0; *(ushort4*)(hhi + off + 4) = oh1;
  *(ushort4*)(hlo + off) = ol0; *(ushort4*)(hlo + off + 4) = ol1;
}

__global__ void k_apply2(const u16* __restrict__ zhi, const u16* __restrict__ zlo,
                         const float* __restrict__ scale, const float* __restrict__ shift,
                         float* __restrict__ hout, float* __restrict__ fout, int dorelu){
  int idx = blockIdx.x * 256 + threadIdx.x;       // 8 elems each, NODES*256 total
  int row = idx >> 5;
  int c0  = (idx & 31) * 8;
  if (row >= NODES) return;
  size_t off = (size_t)row * EMB + c0;
  ushort4 h0 = *(const ushort4*)(zhi + off);
  ushort4 h1 = *(const ushort4*)(zhi + off + 4);
  ushort4 l0 = *(const ushort4*)(zlo + off);
  ushort4 l1 = *(const ushort4*)(zlo + off + 4);
  float4 sA = *(const float4*)(scale + c0), sB = *(const float4*)(scale + c0 + 4);
  float4 tA = *(const float4*)(shift + c0), tB = *(const float4*)(shift + c0 + 4);
  float r0 = (bf2f(h0.x)+bf2f(l0.x))*sA.x + tA.x;
  float r1 = (bf2f(h0.y)+bf2f(l0.y))*sA.y + tA.y;
  float r2 = (bf2f(h0.z)+bf2f(l0.z))*sA.z + tA.z;
  float r3 = (bf2f(h0.w)+bf2f(l0.w))*sA.w + tA.w;
  float r4 = (bf2f(h1.x)+bf2f(l1.x))*sB.x + tB.x;
  float r5 = (bf2f(h1.y)+bf2f(l1.y))*sB.y + tB.y;
  float r6 = (bf2f(h1.z)+bf2f(l1.z))*sB.z + tB.z;
  float r7 = (bf2f(h1.w)+bf2f(l1.w))*sB.w + tB.w;
  if (dorelu){
    r0=fmaxf(r0,0.f); r1=fmaxf(r1,0.f); r2=fmaxf(r2,0.f); r3=fmaxf(r3,0.f);
    r4=fmaxf(r4,0.f); r5=fmaxf(r5,0.f); r6=fmaxf(r6,0.f); r7=fmaxf(r7,0.f);
  }
  float4 f0 = {r0,r1,r2,r3}, f1 = {r4,r5,r6,r7};
  float* q = (fout ? fout : hout) + off;
  *(float4*)q = f0; *(float4*)(q + 4) = f1;
}

// ---------------- launch ----------------

extern "C" void kernel_launch(void* const* d_in, const int* in_sizes, int n_in,
                              void* d_out, int out_size, void* d_ws, size_t ws_size,
                              hipStream_t stream){
  const int*   x    = (const int*)  d_in[0];
  const int*   ei   = (const int*)  d_in[1];
  const int*   ea   = (const int*)  d_in[2];
  const float* aemb = (const float*)d_in[3];
  const float* bemb = (const float*)d_in[4];
  const float* epsv = (const float*)d_in[5];
  const float* W1   = (const float*)d_in[6];
  const float* g1   = (const float*)d_in[8];
  const float* be1  = (const float*)d_in[9];
  const float* W2   = (const float*)d_in[10];
  const float* g2   = (const float*)d_in[12];
  const float* be2  = (const float*)d_in[13];
  float* out = (float*)d_out;

  char* p = (char*)d_ws;
  auto take = [&](size_t bytes){ char* r = p; p += (bytes + 255) & ~(size_t)255; return r; };
  float* h    = (float*)take((size_t)NODES*EMB*4);
  u16* zhi    = (u16*)take((size_t)MPAD*EMB*2);     // reused as GEMM2 output
  u16* zlo    = (u16*)take((size_t)MPAD*EMB*2);
  u16* hidhi  = (u16*)take((size_t)MPAD*512*2);
  u16* hidlo  = (u16*)take((size_t)MPAD*512*2);
  u16* W1hi   = (u16*)take((size_t)5*512*256*2);
  u16* W1lo   = (u16*)take((size_t)5*512*256*2);
  u16* W2hi   = (u16*)take((size_t)5*256*512*2);
  u16* W2lo   = (u16*)take((size_t)5*256*512*2);
  float* eb   = (float*)take((size_t)5*216*256*4);
  float* stats= (float*)take((size_t)4*512*4);
  float* csum = stats, *csq = stats + 512, *scale = stats + 1024, *shift = stats + 1536;
  int* counts = (int*)take((size_t)NODES*4);
  int* rs     = (int*)take((size_t)(NODES+1)*4);
  int* fill   = (int*)take((size_t)NODES*4);
  int* csrc   = (int*)take((size_t)EDGES*4);
  int* cattr  = (int*)take((size_t)EDGES*4);

  k_w1t<<<2560, 256, 0, stream>>>(W1, W1hi, W1lo);
  k_w2t<<<2560, 256, 0, stream>>>(W2, W2hi, W2lo);
  k_ebond<<<5*216, 64, 0, stream>>>(bemb, eb);
  k_atom<<<12500, 256, 0, stream>>>(x, aemb, h);
  hipMemsetAsync(counts, 0, (size_t)NODES*4, stream);
  k_hist<<<EDGES/256, 256, 0, stream>>>(ei + EDGES, counts);
  k_scan<<<1, 1024, 0, stream>>>(counts, rs, fill);
  k_scatter<<<EDGES/256, 256, 0, stream>>>(ei, ei + EDGES, ea, fill, csrc, cattr);

  for (int l = 0; l < 5; ++l){
    k_gather<<<MPAD/4, 256, 0, stream>>>(h, eb + (size_t)l*216*256, rs, csrc, cattr, epsv, l, zhi, zlo);
    hipMemsetAsync(stats, 0, 2*512*4, stream);
    k_gemm<256,512><<<dim3(MPAD/128, 4), 256, 0, stream>>>(
        zhi, zlo, W1hi + (size_t)l*512*256, W1lo + (size_t)l*512*256, hidhi, hidlo, csum, csq);
    k_finalize<<<2, 256, 0, stream>>>(csum, csq, g1 + l*512, be1 + l*512, scale, shift, 512);
    k_apply1<<<MPAD*64/256, 256, 0, stream>>>(hidhi, hidlo, scale, shift);
    hipMemsetAsync(stats, 0, 2*512*4, stream);
    k_gemm<512,256><<<dim3(MPAD/128, 2), 256, 0, stream>>>(
        hidhi, hidlo, W2hi + (size_t)l*256*512, W2lo + (size_t)l*256*512, zhi, zlo, csum, csq);
    k_finalize<<<1, 256, 0, stream>>>(csum, csq, g2 + l*256, be2 + l*256, scale, shift, 256);
    if (l < 4)
      k_apply2<<<NODES*32/256, 256, 0, stream>>>(zhi, zlo, scale, shift, h, nullptr, 1);
    else
      k_apply2<<<NODES*32/256, 256, 0, stream>>>(zhi, zlo, scale, shift, nullptr, out, 0);
  }
}

// Round 6
// 1523.807 us; speedup vs baseline: 1.3209x; 1.3209x over previous
//
#include <hip/hip_runtime.h>
#include <stdint.h>

#define NODES 50000
#define EDGES 800000
#define EMB   256
#define MPAD  50048   // 391*128
#define BNEPS 1e-5f

typedef unsigned short u16;
typedef unsigned int   u32;
typedef _Float16 f16;
typedef __attribute__((ext_vector_type(4))) _Float16 f16x4;
typedef __attribute__((ext_vector_type(8))) _Float16 f16x8;
typedef __attribute__((ext_vector_type(4))) float f32x4;

__device__ __forceinline__ void gload16(const void* g, void* l){
  __builtin_amdgcn_global_load_lds((const __attribute__((address_space(1))) void*)g,
                                   (__attribute__((address_space(3))) void*)l, 16, 0, 0);
}

// ---------------- setup kernels ----------------

__global__ void k_w1t(const float* __restrict__ W1, f16* __restrict__ Wt){
  int i = blockIdx.x * 256 + threadIdx.x;          // 5*512*256, dst layout [l][n][k]
  if (i >= 5*512*256) return;
  int k = i & 255, n = (i >> 8) & 511, l = i >> 17;
  Wt[i] = (f16)W1[((size_t)l << 17) + ((size_t)k << 9) + n];
}
__global__ void k_w2t(const float* __restrict__ W2, f16* __restrict__ Wt){
  int i = blockIdx.x * 256 + threadIdx.x;          // 5*256*512, dst layout [l][n][k]
  if (i >= 5*256*512) return;
  int k = i & 511, n = (i >> 9) & 255, l = i >> 17;
  Wt[i] = (f16)W2[((size_t)l << 17) + ((size_t)k << 8) + n];
}

__global__ void k_ebond(const float* __restrict__ bemb, float* __restrict__ eb){
  int l = blockIdx.x / 216, p = blockIdx.x % 216;
  int a0 = p % 6, a1 = (p / 6) % 6, a2 = p / 36;
  int d0 = threadIdx.x * 4;
  const float* b = bemb + (size_t)l * 3 * 6 * 256;
  float4 v0 = *(const float4*)(b + (0*6 + a0)*256 + d0);
  float4 v1 = *(const float4*)(b + (1*6 + a1)*256 + d0);
  float4 v2 = *(const float4*)(b + (2*6 + a2)*256 + d0);
  float4 o; o.x = v0.x+v1.x+v2.x; o.y = v0.y+v1.y+v2.y;
  o.z = v0.z+v1.z+v2.z; o.w = v0.w+v1.w+v2.w;
  *(float4*)(eb + (((size_t)l*216 + p) << 8) + d0) = o;
}

__global__ void k_atom(const int* __restrict__ x, const float* __restrict__ aemb,
                       f16* __restrict__ h){
  int n = blockIdx.x * 4 + (threadIdx.x >> 6);
  int lane = threadIdx.x & 63;
  if (n >= NODES) return;
  int d0 = lane * 4;
  float a0=0.f, a1=0.f, a2=0.f, a3=0.f;
#pragma unroll
  for (int f = 0; f < 9; ++f){
    int v = x[n*9 + f];
    float4 e = *(const float4*)(aemb + (((size_t)f*120 + v) << 8) + d0);
    a0 += e.x; a1 += e.y; a2 += e.z; a3 += e.w;
  }
  f16x4 o = {(f16)a0, (f16)a1, (f16)a2, (f16)a3};
  *(f16x4*)(h + (size_t)n*EMB + d0) = o;
}

// ---------------- CSR build ----------------

__global__ void k_hist(const int* __restrict__ dst, int* __restrict__ counts){
  int e = blockIdx.x * 256 + threadIdx.x;
  if (e < EDGES) atomicAdd(&counts[dst[e]], 1);
}

__global__ void k_scan(const int* __restrict__ counts, int* __restrict__ rs,
                       int* __restrict__ fill){
  __shared__ int part[1024];
  int t = threadIdx.x;
  const int CH = 49;                                // 1024*49 >= 50000
  int begin = t * CH;
  int end = begin + CH; if (end > NODES) end = NODES;
  if (begin > NODES) begin = NODES;
  int s = 0;
  for (int i = begin; i < end; ++i) s += counts[i];
  part[t] = s; __syncthreads();
  for (int off = 1; off < 1024; off <<= 1){
    int v = (t >= off) ? part[t - off] : 0;
    __syncthreads();
    part[t] += v;
    __syncthreads();
  }
  int run = part[t] - s;                            // exclusive prefix
  for (int i = begin; i < end; ++i){
    rs[i] = run; fill[i] = run; run += counts[i];
  }
  if (t == 1023) rs[NODES] = part[1023];
}

__global__ void k_scatter(const int* __restrict__ src, const int* __restrict__ dst,
                          const int* __restrict__ ea, int* __restrict__ fill,
                          int* __restrict__ csrc, int* __restrict__ cattr){
  int e = blockIdx.x * 256 + threadIdx.x;
  if (e >= EDGES) return;
  int d = dst[e];
  int p = atomicAdd(&fill[d], 1);
  csrc[p]  = src[e];
  cattr[p] = ea[e*3+0] + 6*ea[e*3+1] + 36*ea[e*3+2];
}

// ---------------- per-layer kernels ----------------

__global__ void k_gather(const f16* __restrict__ h, const float* __restrict__ ebl,
                         const int* __restrict__ rs, const int* __restrict__ csrc,
                         const int* __restrict__ cattr, const float* __restrict__ epsv,
                         int layer, f16* __restrict__ z){
  int n = blockIdx.x * 4 + (threadIdx.x >> 6);
  int lane = threadIdx.x & 63;
  int d0 = lane * 4;
  if (n >= MPAD) return;
  size_t zoff = (size_t)n * EMB + d0;
  if (n >= NODES){
    *(f16x4*)(z + zoff) = (f16x4){(f16)0.f, (f16)0.f, (f16)0.f, (f16)0.f};
    return;
  }
  float ep = 1.0f + epsv[layer];
  f16x4 hv = *(const f16x4*)(h + (size_t)n*EMB + d0);
  float a0 = ep*(float)hv.x, a1 = ep*(float)hv.y, a2 = ep*(float)hv.z, a3 = ep*(float)hv.w;
  int i1 = rs[n+1];
  for (int i = rs[n]; i < i1; ++i){
    int s  = csrc[i];
    int pa = cattr[i];
    f16x4 hs = *(const f16x4*)(h + (size_t)s*EMB + d0);
    float4 e4 = *(const float4*)(ebl + ((size_t)pa << 8) + d0);
    a0 += fmaxf((float)hs.x + e4.x, 0.f);
    a1 += fmaxf((float)hs.y + e4.y, 0.f);
    a2 += fmaxf((float)hs.z + e4.z, 0.f);
    a3 += fmaxf((float)hs.w + e4.w, 0.f);
  }
  *(f16x4*)(z + zoff) = (f16x4){(f16)a0, (f16)a1, (f16)a2, (f16)a3};
}

// A [M x K] f16 row-major, Bt [NCOL x K] f16 row-major (pre-transposed weights).
// C [M x NCOL] f16 pre-BN; column sum/sumsq accumulated via f32 atomics.
template<int K, int NCOL>
__global__ __launch_bounds__(256)
void k_gemm(const f16* __restrict__ A, const f16* __restrict__ Bt,
            f16* __restrict__ C, float* __restrict__ csum, float* __restrict__ csq){
  __shared__ __align__(16) u16 As[128*64];
  __shared__ __align__(16) u16 Bs[128*64];
  const int tid  = threadIdx.x;
  const int lane = tid & 63;
  const int wid  = tid >> 6;
  const int bm0 = blockIdx.x * 128;
  const int bn0 = blockIdx.y * 128;
  const int wm = (wid >> 1) * 64;
  const int wn = (wid & 1) * 64;

  f32x4 acc[4][4];
#pragma unroll
  for (int m = 0; m < 4; ++m)
#pragma unroll
    for (int n = 0; n < 4; ++n) acc[m][n] = (f32x4){0.f,0.f,0.f,0.f};

  for (int kt = 0; kt < K/64; ++kt){
    __syncthreads();
#pragma unroll
    for (int it = 0; it < 4; ++it){
      int tix = tid + it*256;
      int r = tix >> 3;
      int c = tix & 7;
      int sc = c ^ (r & 7);          // pre-swizzled global source, linear LDS dest
      gload16(A  + (size_t)(bm0 + r)*K + kt*64 + sc*8, (char*)As + tix*16);
      gload16(Bt + (size_t)(bn0 + r)*K + kt*64 + sc*8, (char*)Bs + tix*16);
    }
    __syncthreads();
#pragma unroll
    for (int kk = 0; kk < 2; ++kk){
      f16x8 af[4], bfr[4];
#pragma unroll
      for (int m = 0; m < 4; ++m){
        int row = wm + m*16 + (lane & 15);
        int phys = (kk*4 + (lane >> 4)) ^ (row & 7);
        af[m] = *(const f16x8*)((const char*)As + row*128 + phys*16);
      }
#pragma unroll
      for (int n = 0; n < 4; ++n){
        int row = wn + n*16 + (lane & 15);
        int phys = (kk*4 + (lane >> 4)) ^ (row & 7);
        bfr[n] = *(const f16x8*)((const char*)Bs + row*128 + phys*16);
      }
#pragma unroll
      for (int m = 0; m < 4; ++m)
#pragma unroll
        for (int n = 0; n < 4; ++n)
          acc[m][n] = __builtin_amdgcn_mfma_f32_16x16x32_f16(af[m], bfr[n], acc[m][n], 0, 0, 0);
    }
  }

  const int r0 = (lane >> 4) * 4;
  const int cc = lane & 15;
#pragma unroll
  for (int m = 0; m < 4; ++m)
#pragma unroll
    for (int n = 0; n < 4; ++n)
#pragma unroll
      for (int j = 0; j < 4; ++j){
        int row = bm0 + wm + m*16 + r0 + j;
        int col = bn0 + wn + n*16 + cc;
        C[(size_t)row*NCOL + col] = (f16)acc[m][n][j];
      }
#pragma unroll
  for (int n = 0; n < 4; ++n){
    float s = 0.f, q = 0.f;
#pragma unroll
    for (int m = 0; m < 4; ++m)
#pragma unroll
      for (int j = 0; j < 4; ++j){ float v = acc[m][n][j]; s += v; q += v*v; }
    s += __shfl_xor(s, 16); q += __shfl_xor(q, 16);
    s += __shfl_xor(s, 32); q += __shfl_xor(q, 32);
    if (lane < 16){
      atomicAdd(csum + bn0 + wn + n*16 + cc, s);
      atomicAdd(csq  + bn0 + wn + n*16 + cc, q);
    }
  }
}

__global__ void k_finalize(const float* __restrict__ sum, const float* __restrict__ sumsq,
                           const float* __restrict__ g, const float* __restrict__ be,
                           float* __restrict__ scale, float* __restrict__ shift, int nc){
  int c = blockIdx.x * 256 + threadIdx.x;
  if (c >= nc) return;
  float m = sum[c] * (1.0f / NODES);
  float v = sumsq[c] * (1.0f / NODES) - m*m;
  float sc = rsqrtf(v + BNEPS) * g[c];
  scale[c] = sc;
  shift[c] = be[c] - m*sc;
}

__global__ void k_apply1(f16* __restrict__ hid, const float* __restrict__ scale,
                         const float* __restrict__ shift){
  int idx = blockIdx.x * 256 + threadIdx.x;       // 8 elems each, MPAD*512 total
  int row = idx >> 6;
  int c0  = (idx & 63) * 8;
  f16* p = hid + (size_t)row * 512 + c0;
  if (row >= NODES){
    f16x8 zz = {(f16)0.f,(f16)0.f,(f16)0.f,(f16)0.f,(f16)0.f,(f16)0.f,(f16)0.f,(f16)0.f};
    *(f16x8*)p = zz;
    return;
  }
  f16x8 v = *(const f16x8*)p;
  float4 sA = *(const float4*)(scale + c0), sB = *(const float4*)(scale + c0 + 4);
  float4 tA = *(const float4*)(shift + c0), tB = *(const float4*)(shift + c0 + 4);
  f16x8 o;
  o[0] = (f16)fmaxf((float)v[0]*sA.x + tA.x, 0.f);
  o[1] = (f16)fmaxf((float)v[1]*sA.y + tA.y, 0.f);
  o[2] = (f16)fmaxf((float)v[2]*sA.z + tA.z, 0.f);
  o[3] = (f16)fmaxf((float)v[3]*sA.w + tA.w, 0.f);
  o[4] = (f16)fmaxf((float)v[4]*sB.x + tB.x, 0.f);
  o[5] = (f16)fmaxf((float)v[5]*sB.y + tB.y, 0.f);
  o[6] = (f16)fmaxf((float)v[6]*sB.z + tB.z, 0.f);
  o[7] = (f16)fmaxf((float)v[7]*sB.w + tB.w, 0.f);
  *(f16x8*)p = o;
}

__global__ void k_apply2(const f16* __restrict__ zp, const float* __restrict__ scale,
                         const float* __restrict__ shift, f16* __restrict__ hout,
                         float* __restrict__ fout, int dorelu){
  int idx = blockIdx.x * 256 + threadIdx.x;       // 8 elems each, NODES*256 total
  int row = idx >> 5;
  int c0  = (idx & 31) * 8;
  if (row >= NODES) return;
  size_t off = (size_t)row * EMB + c0;
  f16x8 v = *(const f16x8*)(zp + off);
  float4 sA = *(const float4*)(scale + c0), sB = *(const float4*)(scale + c0 + 4);
  float4 tA = *(const float4*)(shift + c0), tB = *(const float4*)(shift + c0 + 4);
  float r0 = (float)v[0]*sA.x + tA.x;
  float r1 = (float)v[1]*sA.y + tA.y;
  float r2 = (float)v[2]*sA.z + tA.z;
  float r3 = (float)v[3]*sA.w + tA.w;
  float r4 = (float)v[4]*sB.x + tB.x;
  float r5 = (float)v[5]*sB.y + tB.y;
  float r6 = (float)v[6]*sB.z + tB.z;
  float r7 = (float)v[7]*sB.w + tB.w;
  if (dorelu){
    r0=fmaxf(r0,0.f); r1=fmaxf(r1,0.f); r2=fmaxf(r2,0.f); r3=fmaxf(r3,0.f);
    r4=fmaxf(r4,0.f); r5=fmaxf(r5,0.f); r6=fmaxf(r6,0.f); r7=fmaxf(r7,0.f);
  }
  if (fout){
    float4 f0 = {r0,r1,r2,r3}, f1 = {r4,r5,r6,r7};
    float* q = fout + off;
    *(float4*)q = f0; *(float4*)(q + 4) = f1;
  } else {
    f16x8 o = {(f16)r0,(f16)r1,(f16)r2,(f16)r3,(f16)r4,(f16)r5,(f16)r6,(f16)r7};
    *(f16x8*)(hout + off) = o;
  }
}

// ---------------- launch ----------------

extern "C" void kernel_launch(void* const* d_in, const int* in_sizes, int n_in,
                              void* d_out, int out_size, void* d_ws, size_t ws_size,
                              hipStream_t stream){
  const int*   x    = (const int*)  d_in[0];
  const int*   ei   = (const int*)  d_in[1];
  const int*   ea   = (const int*)  d_in[2];
  const float* aemb = (const float*)d_in[3];
  const float* bemb = (const float*)d_in[4];
  const float* epsv = (const float*)d_in[5];
  const float* W1   = (const float*)d_in[6];
  const float* g1   = (const float*)d_in[8];
  const float* be1  = (const float*)d_in[9];
  const float* W2   = (const float*)d_in[10];
  const float* g2   = (const float*)d_in[12];
  const float* be2  = (const float*)d_in[13];
  float* out = (float*)d_out;

  char* p = (char*)d_ws;
  auto take = [&](size_t bytes){ char* r = p; p += (bytes + 255) & ~(size_t)255; return r; };
  f16* h      = (f16*)take((size_t)NODES*EMB*2);
  f16* z      = (f16*)take((size_t)MPAD*EMB*2);     // reused as GEMM2 output
  f16* hidden = (f16*)take((size_t)MPAD*512*2);
  f16* W1t    = (f16*)take((size_t)5*512*256*2);
  f16* W2t    = (f16*)take((size_t)5*256*512*2);
  float* eb   = (float*)take((size_t)5*216*256*4);
  float* stats= (float*)take((size_t)4*512*4);
  float* csum = stats, *csq = stats + 512, *scale = stats + 1024, *shift = stats + 1536;
  int* counts = (int*)take((size_t)NODES*4);
  int* rs     = (int*)take((size_t)(NODES+1)*4);
  int* fill   = (int*)take((size_t)NODES*4);
  int* csrc   = (int*)take((size_t)EDGES*4);
  int* cattr  = (int*)take((size_t)EDGES*4);

  k_w1t<<<2560, 256, 0, stream>>>(W1, W1t);
  k_w2t<<<2560, 256, 0, stream>>>(W2, W2t);
  k_ebond<<<5*216, 64, 0, stream>>>(bemb, eb);
  k_atom<<<12500, 256, 0, stream>>>(x, aemb, h);
  hipMemsetAsync(counts, 0, (size_t)NODES*4, stream);
  k_hist<<<EDGES/256, 256, 0, stream>>>(ei + EDGES, counts);
  k_scan<<<1, 1024, 0, stream>>>(counts, rs, fill);
  k_scatter<<<EDGES/256, 256, 0, stream>>>(ei, ei + EDGES, ea, fill, csrc, cattr);

  for (int l = 0; l < 5; ++l){
    k_gather<<<MPAD/4, 256, 0, stream>>>(h, eb + (size_t)l*216*256, rs, csrc, cattr, epsv, l, z);
    hipMemsetAsync(stats, 0, 2*512*4, stream);
    k_gemm<256,512><<<dim3(MPAD/128, 4), 256, 0, stream>>>(z, W1t + (size_t)l*512*256, hidden, csum, csq);
    k_finalize<<<2, 256, 0, stream>>>(csum, csq, g1 + l*512, be1 + l*512, scale, shift, 512);
    k_apply1<<<MPAD*64/256, 256, 0, stream>>>(hidden, scale, shift);
    hipMemsetAsync(stats, 0, 2*512*4, stream);
    k_gemm<512,256><<<dim3(MPAD/128, 2), 256, 0, stream>>>(hidden, W2t + (size_t)l*256*512, z, csum, csq);
    k_finalize<<<1, 256, 0, stream>>>(csum, csq, g2 + l*256, be2 + l*256, scale, shift, 256);
    if (l < 4)
      k_apply2<<<NODES*32/256, 256, 0, stream>>>(z, scale, shift, h, nullptr, 1);
    else
      k_apply2<<<NODES*32/256, 256, 0, stream>>>(z, scale, shift, nullptr, out, 0);
  }
}

// Round 8
// 1437.223 us; speedup vs baseline: 1.4004x; 1.0602x over previous
//
#include <hip/hip_runtime.h>
#include <stdint.h>

#define NODES 50000
#define EDGES 800000
#define EMB   256
#define MPAD  50048   // 391*128
#define BNEPS 1e-5f
#define SCANB 196     // 196*256 = 50176 >= NODES

typedef unsigned short u16;
typedef unsigned int   u32;
typedef _Float16 f16;
typedef __attribute__((ext_vector_type(4))) _Float16 f16x4;
typedef __attribute__((ext_vector_type(8))) _Float16 f16x8;
typedef __attribute__((ext_vector_type(4))) float f32x4;

__device__ __forceinline__ void gload16(const void* g, void* l){
  __builtin_amdgcn_global_load_lds((const __attribute__((address_space(1))) void*)g,
                                   (__attribute__((address_space(3))) void*)l, 16, 0, 0);
}

// ---------------- setup kernels ----------------

__global__ void k_w1t(const float* __restrict__ W1, f16* __restrict__ Wt){
  int i = blockIdx.x * 256 + threadIdx.x;          // 5*512*256, dst layout [l][n][k]
  if (i >= 5*512*256) return;
  int k = i & 255, n = (i >> 8) & 511, l = i >> 17;
  Wt[i] = (f16)W1[((size_t)l << 17) + ((size_t)k << 9) + n];
}
__global__ void k_w2t(const float* __restrict__ W2, f16* __restrict__ Wt){
  int i = blockIdx.x * 256 + threadIdx.x;          // 5*256*512, dst layout [l][n][k]
  if (i >= 5*256*512) return;
  int k = i & 511, n = (i >> 9) & 255, l = i >> 17;
  Wt[i] = (f16)W2[((size_t)l << 17) + ((size_t)k << 8) + n];
}

__global__ void k_ebond(const float* __restrict__ bemb, f16* __restrict__ eb){
  int l = blockIdx.x / 216, p = blockIdx.x % 216;
  int a0 = p % 6, a1 = (p / 6) % 6, a2 = p / 36;
  int d0 = threadIdx.x * 4;
  const float* b = bemb + (size_t)l * 3 * 6 * 256;
  float4 v0 = *(const float4*)(b + (0*6 + a0)*256 + d0);
  float4 v1 = *(const float4*)(b + (1*6 + a1)*256 + d0);
  float4 v2 = *(const float4*)(b + (2*6 + a2)*256 + d0);
  f16x4 o = {(f16)(v0.x+v1.x+v2.x), (f16)(v0.y+v1.y+v2.y),
             (f16)(v0.z+v1.z+v2.z), (f16)(v0.w+v1.w+v2.w)};
  *(f16x4*)(eb + (((size_t)l*216 + p) << 8) + d0) = o;
}

__global__ void k_atom(const int* __restrict__ x, const float* __restrict__ aemb,
                       f16* __restrict__ h){
  int n = blockIdx.x * 4 + (threadIdx.x >> 6);
  int lane = threadIdx.x & 63;
  if (n >= NODES) return;
  int d0 = lane * 4;
  float a0=0.f, a1=0.f, a2=0.f, a3=0.f;
#pragma unroll
  for (int f = 0; f < 9; ++f){
    int v = x[n*9 + f];
    float4 e = *(const float4*)(aemb + (((size_t)f*120 + v) << 8) + d0);
    a0 += e.x; a1 += e.y; a2 += e.z; a3 += e.w;
  }
  f16x4 o = {(f16)a0, (f16)a1, (f16)a2, (f16)a3};
  *(f16x4*)(h + (size_t)n*EMB + d0) = o;
}

// ---------------- CSR build ----------------

__global__ void k_hist(const int* __restrict__ dst, int* __restrict__ counts){
  int e = blockIdx.x * 256 + threadIdx.x;
  if (e < EDGES) atomicAdd(&counts[dst[e]], 1);
}

// phase 1: per-block sums of counts (256 nodes per block)
__global__ void k_bsum(const int* __restrict__ counts, int* __restrict__ bsums){
  __shared__ int red[256];
  int t = threadIdx.x;
  int i = blockIdx.x * 256 + t;
  red[t] = (i < NODES) ? counts[i] : 0;
  __syncthreads();
  for (int off = 128; off > 0; off >>= 1){
    if (t < off) red[t] += red[t + off];
    __syncthreads();
  }
  if (t == 0) bsums[blockIdx.x] = red[0];
}

// phase 2: exclusive scan of SCANB block sums (single small block)
__global__ void k_bscan(int* __restrict__ bsums){
  __shared__ int sc[256];
  int t = threadIdx.x;
  int v = (t < SCANB) ? bsums[t] : 0;
  sc[t] = v;
  __syncthreads();
  for (int off = 1; off < 256; off <<= 1){
    int u = (t >= off) ? sc[t - off] : 0;
    __syncthreads();
    sc[t] += u;
    __syncthreads();
  }
  if (t < SCANB) bsums[t] = sc[t] - v;              // exclusive
}

// phase 3: per-block exclusive scan + block offset -> rs, fill
__global__ void k_fill(const int* __restrict__ counts, const int* __restrict__ bsums,
                       int* __restrict__ rs, int* __restrict__ fill){
  __shared__ int sc[256];
  int t = threadIdx.x;
  int i = blockIdx.x * 256 + t;
  int v = (i < NODES) ? counts[i] : 0;
  sc[t] = v;
  __syncthreads();
  for (int off = 1; off < 256; off <<= 1){
    int u = (t >= off) ? sc[t - off] : 0;
    __syncthreads();
    sc[t] += u;
    __syncthreads();
  }
  if (i < NODES){
    int e = bsums[blockIdx.x] + sc[t] - v;          // exclusive prefix
    rs[i] = e; fill[i] = e;
    if (i == NODES - 1) rs[NODES] = e + v;
  }
}

__global__ void k_scatter(const int* __restrict__ src, const int* __restrict__ dst,
                          const int* __restrict__ ea, int* __restrict__ fill,
                          int* __restrict__ csrc, int* __restrict__ cattr){
  int e = blockIdx.x * 256 + threadIdx.x;
  if (e >= EDGES) return;
  int d = dst[e];
  int p = atomicAdd(&fill[d], 1);
  csrc[p]  = src[e];
  cattr[p] = ea[e*3+0] + 6*ea[e*3+1] + 36*ea[e*3+2];
}

// ---------------- per-layer kernels ----------------

__global__ void k_gather(const f16* __restrict__ h, const f16* __restrict__ ebl,
                         const int* __restrict__ rs, const int* __restrict__ csrc,
                         const int* __restrict__ cattr, const float* __restrict__ epsv,
                         int layer, f16* __restrict__ z){
  int n = blockIdx.x * 4 + (threadIdx.x >> 6);
  int lane = threadIdx.x & 63;
  int d0 = lane * 4;
  if (n >= MPAD) return;
  size_t zoff = (size_t)n * EMB + d0;
  if (n >= NODES){
    *(f16x4*)(z + zoff) = (f16x4){(f16)0.f, (f16)0.f, (f16)0.f, (f16)0.f};
    return;
  }
  float ep = 1.0f + epsv[layer];
  f16x4 hv = *(const f16x4*)(h + (size_t)n*EMB + d0);
  float a0 = ep*(float)hv.x, a1 = ep*(float)hv.y, a2 = ep*(float)hv.z, a3 = ep*(float)hv.w;
  int i1 = rs[n+1];
  for (int i = rs[n]; i < i1; ++i){
    int s  = csrc[i];
    int pa = cattr[i];
    f16x4 hs = *(const f16x4*)(h + (size_t)s*EMB + d0);
    f16x4 e4 = *(const f16x4*)(ebl + ((size_t)pa << 8) + d0);
    a0 += fmaxf((float)hs.x + (float)e4.x, 0.f);
    a1 += fmaxf((float)hs.y + (float)e4.y, 0.f);
    a2 += fmaxf((float)hs.z + (float)e4.z, 0.f);
    a3 += fmaxf((float)hs.w + (float)e4.w, 0.f);
  }
  *(f16x4*)(z + zoff) = (f16x4){(f16)a0, (f16)a1, (f16)a2, (f16)a3};
}

// A [M x K] f16 row-major, Bt [NCOL x K] f16 row-major (pre-transposed weights).
// C [M x NCOL] f16 pre-BN; column sum/sumsq accumulated via f32 atomics.
template<int K, int NCOL>
__global__ __launch_bounds__(256)
void k_gemm(const f16* __restrict__ A, const f16* __restrict__ Bt,
            f16* __restrict__ C, float* __restrict__ csum, float* __restrict__ csq){
  __shared__ __align__(16) u16 As[128*64];
  __shared__ __align__(16) u16 Bs[128*64];
  const int tid  = threadIdx.x;
  const int lane = tid & 63;
  const int wid  = tid >> 6;
  const int bm0 = blockIdx.x * 128;
  const int bn0 = blockIdx.y * 128;
  const int wm = (wid >> 1) * 64;
  const int wn = (wid & 1) * 64;

  f32x4 acc[4][4];
#pragma unroll
  for (int m = 0; m < 4; ++m)
#pragma unroll
    for (int n = 0; n < 4; ++n) acc[m][n] = (f32x4){0.f,0.f,0.f,0.f};

  for (int kt = 0; kt < K/64; ++kt){
    __syncthreads();
#pragma unroll
    for (int it = 0; it < 4; ++it){
      int tix = tid + it*256;
      int r = tix >> 3;
      int c = tix & 7;
      int sc = c ^ (r & 7);          // pre-swizzled global source, linear LDS dest
      gload16(A  + (size_t)(bm0 + r)*K + kt*64 + sc*8, (char*)As + tix*16);
      gload16(Bt + (size_t)(bn0 + r)*K + kt*64 + sc*8, (char*)Bs + tix*16);
    }
    __syncthreads();
#pragma unroll
    for (int kk = 0; kk < 2; ++kk){
      f16x8 af[4], bfr[4];
#pragma unroll
      for (int m = 0; m < 4; ++m){
        int row = wm + m*16 + (lane & 15);
        int phys = (kk*4 + (lane >> 4)) ^ (row & 7);
        af[m] = *(const f16x8*)((const char*)As + row*128 + phys*16);
      }
#pragma unroll
      for (int n = 0; n < 4; ++n){
        int row = wn + n*16 + (lane & 15);
        int phys = (kk*4 + (lane >> 4)) ^ (row & 7);
        bfr[n] = *(const f16x8*)((const char*)Bs + row*128 + phys*16);
      }
#pragma unroll
      for (int m = 0; m < 4; ++m)
#pragma unroll
        for (int n = 0; n < 4; ++n)
          acc[m][n] = __builtin_amdgcn_mfma_f32_16x16x32_f16(af[m], bfr[n], acc[m][n], 0, 0, 0);
    }
  }

  const int r0 = (lane >> 4) * 4;
  const int cc = lane & 15;
#pragma unroll
  for (int m = 0; m < 4; ++m)
#pragma unroll
    for (int n = 0; n < 4; ++n)
#pragma unroll
      for (int j = 0; j < 4; ++j){
        int row = bm0 + wm + m*16 + r0 + j;
        int col = bn0 + wn + n*16 + cc;
        C[(size_t)row*NCOL + col] = (f16)acc[m][n][j];
      }
#pragma unroll
  for (int n = 0; n < 4; ++n){
    float s = 0.f, q = 0.f;
#pragma unroll
    for (int m = 0; m < 4; ++m)
#pragma unroll
      for (int j = 0; j < 4; ++j){ float v = acc[m][n][j]; s += v; q += v*v; }
    s += __shfl_xor(s, 16); q += __shfl_xor(q, 16);
    s += __shfl_xor(s, 32); q += __shfl_xor(q, 32);
    if (lane < 16){
      atomicAdd(csum + bn0 + wn + n*16 + cc, s);
      atomicAdd(csq  + bn0 + wn + n*16 + cc, q);
    }
  }
}

__global__ void k_finalize(const float* __restrict__ sum, const float* __restrict__ sumsq,
                           const float* __restrict__ g, const float* __restrict__ be,
                           float* __restrict__ scale, float* __restrict__ shift, int nc){
  int c = blockIdx.x * 256 + threadIdx.x;
  if (c >= nc) return;
  float m = sum[c] * (1.0f / NODES);
  float v = sumsq[c] * (1.0f / NODES) - m*m;
  float sc = rsqrtf(v + BNEPS) * g[c];
  scale[c] = sc;
  shift[c] = be[c] - m*sc;
}

__global__ void k_apply1(f16* __restrict__ hid, const float* __restrict__ scale,
                         const float* __restrict__ shift){
  int idx = blockIdx.x * 256 + threadIdx.x;       // 8 elems each, MPAD*512 total
  int row = idx >> 6;
  int c0  = (idx & 63) * 8;
  f16* p = hid + (size_t)row * 512 + c0;
  if (row >= NODES){
    f16x8 zz = {(f16)0.f,(f16)0.f,(f16)0.f,(f16)0.f,(f16)0.f,(f16)0.f,(f16)0.f,(f16)0.f};
    *(f16x8*)p = zz;
    return;
  }
  f16x8 v = *(const f16x8*)p;
  float4 sA = *(const float4*)(scale + c0), sB = *(const float4*)(scale + c0 + 4);
  float4 tA = *(const float4*)(shift + c0), tB = *(const float4*)(shift + c0 + 4);
  f16x8 o;
  o[0] = (f16)fmaxf((float)v[0]*sA.x + tA.x, 0.f);
  o[1] = (f16)fmaxf((float)v[1]*sA.y + tA.y, 0.f);
  o[2] = (f16)fmaxf((float)v[2]*sA.z + tA.z, 0.f);
  o[3] = (f16)fmaxf((float)v[3]*sA.w + tA.w, 0.f);
  o[4] = (f16)fmaxf((float)v[4]*sB.x + tB.x, 0.f);
  o[5] = (f16)fmaxf((float)v[5]*sB.y + tB.y, 0.f);
  o[6] = (f16)fmaxf((float)v[6]*sB.z + tB.z, 0.f);
  o[7] = (f16)fmaxf((float)v[7]*sB.w + tB.w, 0.f);
  *(f16x8*)p = o;
}

__global__ void k_apply2(const f16* __restrict__ zp, const float* __restrict__ scale,
                         const float* __restrict__ shift, f16* __restrict__ hout,
                         float* __restrict__ fout, int dorelu){
  int idx = blockIdx.x * 256 + threadIdx.x;       // 8 elems each, NODES*256 total
  int row = idx >> 5;
  int c0  = (idx & 31) * 8;
  if (row >= NODES) return;
  size_t off = (size_t)row * EMB + c0;
  f16x8 v = *(const f16x8*)(zp + off);
  float4 sA = *(const float4*)(scale + c0), sB = *(const float4*)(scale + c0 + 4);
  float4 tA = *(const float4*)(shift + c0), tB = *(const float4*)(shift + c0 + 4);
  float r0 = (float)v[0]*sA.x + tA.x;
  float r1 = (float)v[1]*sA.y + tA.y;
  float r2 = (float)v[2]*sA.z + tA.z;
  float r3 = (float)v[3]*sA.w + tA.w;
  float r4 = (float)v[4]*sB.x + tB.x;
  float r5 = (float)v[5]*sB.y + tB.y;
  float r6 = (float)v[6]*sB.z + tB.z;
  float r7 = (float)v[7]*sB.w + tB.w;
  if (dorelu){
    r0=fmaxf(r0,0.f); r1=fmaxf(r1,0.f); r2=fmaxf(r2,0.f); r3=fmaxf(r3,0.f);
    r4=fmaxf(r4,0.f); r5=fmaxf(r5,0.f); r6=fmaxf(r6,0.f); r7=fmaxf(r7,0.f);
  }
  if (fout){
    float4 f0 = {r0,r1,r2,r3}, f1 = {r4,r5,r6,r7};
    float* q = fout + off;
    *(float4*)q = f0; *(float4*)(q + 4) = f1;
  } else {
    f16x8 o = {(f16)r0,(f16)r1,(f16)r2,(f16)r3,(f16)r4,(f16)r5,(f16)r6,(f16)r7};
    *(f16x8*)(hout + off) = o;
  }
}

// ---------------- launch ----------------

extern "C" void kernel_launch(void* const* d_in, const int* in_sizes, int n_in,
                              void* d_out, int out_size, void* d_ws, size_t ws_size,
                              hipStream_t stream){
  const int*   x    = (const int*)  d_in[0];
  const int*   ei   = (const int*)  d_in[1];
  const int*   ea   = (const int*)  d_in[2];
  const float* aemb = (const float*)d_in[3];
  const float* bemb = (const float*)d_in[4];
  const float* epsv = (const float*)d_in[5];
  const float* W1   = (const float*)d_in[6];
  const float* g1   = (const float*)d_in[8];
  const float* be1  = (const float*)d_in[9];
  const float* W2   = (const float*)d_in[10];
  const float* g2   = (const float*)d_in[12];
  const float* be2  = (const float*)d_in[13];
  float* out = (float*)d_out;

  char* p = (char*)d_ws;
  auto take = [&](size_t bytes){ char* r = p; p += (bytes + 255) & ~(size_t)255; return r; };
  f16* h      = (f16*)take((size_t)NODES*EMB*2);
  f16* z      = (f16*)take((size_t)MPAD*EMB*2);     // reused as GEMM2 output
  f16* hidden = (f16*)take((size_t)MPAD*512*2);
  f16* W1t    = (f16*)take((size_t)5*512*256*2);
  f16* W2t    = (f16*)take((size_t)5*256*512*2);
  f16* eb     = (f16*)take((size_t)5*216*256*2);
  float* stats= (float*)take((size_t)4*512*4);
  float* csum = stats, *csq = stats + 512, *scale = stats + 1024, *shift = stats + 1536;
  int* counts = (int*)take((size_t)NODES*4);
  int* rs     = (int*)take((size_t)(NODES+1)*4);
  int* fill   = (int*)take((size_t)NODES*4);
  int* bsums  = (int*)take((size_t)SCANB*4);
  int* csrc   = (int*)take((size_t)EDGES*4);
  int* cattr  = (int*)take((size_t)EDGES*4);

  k_w1t<<<2560, 256, 0, stream>>>(W1, W1t);
  k_w2t<<<2560, 256, 0, stream>>>(W2, W2t);
  k_ebond<<<5*216, 64, 0, stream>>>(bemb, eb);
  k_atom<<<12500, 256, 0, stream>>>(x, aemb, h);
  hipMemsetAsync(counts, 0, (size_t)NODES*4, stream);
  k_hist<<<EDGES/256, 256, 0, stream>>>(ei + EDGES, counts);
  k_bsum<<<SCANB, 256, 0, stream>>>(counts, bsums);
  k_bscan<<<1, 256, 0, stream>>>(bsums);
  k_fill<<<SCANB, 256, 0, stream>>>(counts, bsums, rs, fill);
  k_scatter<<<EDGES/256, 256, 0, stream>>>(ei, ei + EDGES, ea, fill, csrc, cattr);

  for (int l = 0; l < 5; ++l){
    k_gather<<<MPAD/4, 256, 0, stream>>>(h, eb + (size_t)l*216*256, rs, csrc, cattr, epsv, l, z);
    hipMemsetAsync(stats, 0, 2*512*4, stream);
    k_gemm<256,512><<<dim3(MPAD/128, 4), 256, 0, stream>>>(z, W1t + (size_t)l*512*256, hidden, csum, csq);
    k_finalize<<<2, 256, 0, stream>>>(csum, csq, g1 + l*512, be1 + l*512, scale, shift, 512);
    k_apply1<<<MPAD*64/256, 256, 0, stream>>>(hidden, scale, shift);
    hipMemsetAsync(stats, 0, 2*512*4, stream);
    k_gemm<512,256><<<dim3(MPAD/128, 2), 256, 0, stream>>>(hidden, W2t + (size_t)l*256*512, z, csum, csq);
    k_finalize<<<1, 256, 0, stream>>>(csum, csq, g2 + l*256, be2 + l*256, scale, shift, 256);
    if (l < 4)
      k_apply2<<<NODES*32/256, 256, 0, stream>>>(z, scale, shift, h, nullptr, 1);
    else
      k_apply2<<<NODES*32/256, 256, 0, stream>>>(z, scale, shift, nullptr, out, 0);
  }
}

// Round 9
// 1241.569 us; speedup vs baseline: 1.6211x; 1.1576x over previous
//
#include <hip/hip_runtime.h>
#include <stdint.h>

#define NODES 50000
#define EDGES 800000
#define EMB   256
#define MPAD  50048   // 391*128
#define BNEPS 1e-5f
#define SCANB 196     // 196*256 = 50176 >= NODES

typedef unsigned short u16;
typedef unsigned int   u32;
typedef _Float16 f16;
typedef __attribute__((ext_vector_type(4))) _Float16 f16x4;
typedef __attribute__((ext_vector_type(8))) _Float16 f16x8;
typedef __attribute__((ext_vector_type(4))) float f32x4;

__device__ __forceinline__ void gload16(const void* g, void* l){
  __builtin_amdgcn_global_load_lds((const __attribute__((address_space(1))) void*)g,
                                   (__attribute__((address_space(3))) void*)l, 16, 0, 0);
}

// ---------------- setup kernels ----------------

__global__ void k_w1t(const float* __restrict__ W1, f16* __restrict__ Wt){
  int i = blockIdx.x * 256 + threadIdx.x;          // 5*512*256, dst layout [l][n][k]
  if (i >= 5*512*256) return;
  int k = i & 255, n = (i >> 8) & 511, l = i >> 17;
  Wt[i] = (f16)W1[((size_t)l << 17) + ((size_t)k << 9) + n];
}
__global__ void k_w2t(const float* __restrict__ W2, f16* __restrict__ Wt){
  int i = blockIdx.x * 256 + threadIdx.x;          // 5*256*512, dst layout [l][n][k]
  if (i >= 5*256*512) return;
  int k = i & 511, n = (i >> 9) & 255, l = i >> 17;
  Wt[i] = (f16)W2[((size_t)l << 17) + ((size_t)k << 8) + n];
}

__global__ void k_ebond(const float* __restrict__ bemb, f16* __restrict__ eb){
  int l = blockIdx.x / 216, p = blockIdx.x % 216;
  int a0 = p % 6, a1 = (p / 6) % 6, a2 = p / 36;
  int d0 = threadIdx.x * 4;
  const float* b = bemb + (size_t)l * 3 * 6 * 256;
  float4 v0 = *(const float4*)(b + (0*6 + a0)*256 + d0);
  float4 v1 = *(const float4*)(b + (1*6 + a1)*256 + d0);
  float4 v2 = *(const float4*)(b + (2*6 + a2)*256 + d0);
  f16x4 o = {(f16)(v0.x+v1.x+v2.x), (f16)(v0.y+v1.y+v2.y),
             (f16)(v0.z+v1.z+v2.z), (f16)(v0.w+v1.w+v2.w)};
  *(f16x4*)(eb + (((size_t)l*216 + p) << 8) + d0) = o;
}

__global__ void k_atom(const int* __restrict__ x, const float* __restrict__ aemb,
                       f16* __restrict__ h){
  int n = blockIdx.x * 4 + (threadIdx.x >> 6);
  int lane = threadIdx.x & 63;
  if (n >= NODES) return;
  int d0 = lane * 4;
  float a0=0.f, a1=0.f, a2=0.f, a3=0.f;
#pragma unroll
  for (int f = 0; f < 9; ++f){
    int v = x[n*9 + f];
    float4 e = *(const float4*)(aemb + (((size_t)f*120 + v) << 8) + d0);
    a0 += e.x; a1 += e.y; a2 += e.z; a3 += e.w;
  }
  f16x4 o = {(f16)a0, (f16)a1, (f16)a2, (f16)a3};
  *(f16x4*)(h + (size_t)n*EMB + d0) = o;
}

// ---------------- CSR build ----------------

__global__ void k_hist(const int* __restrict__ dst, int* __restrict__ counts){
  int e = blockIdx.x * 256 + threadIdx.x;
  if (e < EDGES) atomicAdd(&counts[dst[e]], 1);
}

// phase 1: per-block sums of counts (256 nodes per block)
__global__ void k_bsum(const int* __restrict__ counts, int* __restrict__ bsums){
  __shared__ int red[256];
  int t = threadIdx.x;
  int i = blockIdx.x * 256 + t;
  red[t] = (i < NODES) ? counts[i] : 0;
  __syncthreads();
  for (int off = 128; off > 0; off >>= 1){
    if (t < off) red[t] += red[t + off];
    __syncthreads();
  }
  if (t == 0) bsums[blockIdx.x] = red[0];
}

// phase 2: exclusive scan of SCANB block sums (single small block)
__global__ void k_bscan(int* __restrict__ bsums){
  __shared__ int sc[256];
  int t = threadIdx.x;
  int v = (t < SCANB) ? bsums[t] : 0;
  sc[t] = v;
  __syncthreads();
  for (int off = 1; off < 256; off <<= 1){
    int u = (t >= off) ? sc[t - off] : 0;
    __syncthreads();
    sc[t] += u;
    __syncthreads();
  }
  if (t < SCANB) bsums[t] = sc[t] - v;              // exclusive
}

// phase 3: per-block exclusive scan + block offset -> rs, fill
__global__ void k_fill(const int* __restrict__ counts, const int* __restrict__ bsums,
                       int* __restrict__ rs, int* __restrict__ fill){
  __shared__ int sc[256];
  int t = threadIdx.x;
  int i = blockIdx.x * 256 + t;
  int v = (i < NODES) ? counts[i] : 0;
  sc[t] = v;
  __syncthreads();
  for (int off = 1; off < 256; off <<= 1){
    int u = (t >= off) ? sc[t - off] : 0;
    __syncthreads();
    sc[t] += u;
    __syncthreads();
  }
  if (i < NODES){
    int e = bsums[blockIdx.x] + sc[t] - v;          // exclusive prefix
    rs[i] = e; fill[i] = e;
    if (i == NODES - 1) rs[NODES] = e + v;
  }
}

__global__ void k_scatter(const int* __restrict__ src, const int* __restrict__ dst,
                          const int* __restrict__ ea, int* __restrict__ fill,
                          int* __restrict__ csrc, int* __restrict__ cattr){
  int e = blockIdx.x * 256 + threadIdx.x;
  if (e >= EDGES) return;
  int d = dst[e];
  int p = atomicAdd(&fill[d], 1);
  csrc[p]  = src[e];
  cattr[p] = ea[e*3+0] + 6*ea[e*3+1] + 36*ea[e*3+2];
}

// ---------------- per-layer kernels ----------------

// One wave per node. Half-wave edge pairing: lanes 0-31 process even edges,
// lanes 32-63 odd edges; each lane covers 8 dims (16B f16x8 loads). Index
// loads for edge i+2 issued before consuming edge i (software pipeline).
__global__ void k_gather(const f16* __restrict__ h, const f16* __restrict__ ebl,
                         const int* __restrict__ rs, const int* __restrict__ csrc,
                         const int* __restrict__ cattr, const float* __restrict__ epsv,
                         int layer, f16* __restrict__ z){
  int n = blockIdx.x * 4 + (threadIdx.x >> 6);
  int lane = threadIdx.x & 63;
  int half = lane >> 5;
  int dl = (lane & 31) * 8;
  if (n >= MPAD) return;
  if (n >= NODES){
    if (half == 0){
      f16x8 zz = {(f16)0.f,(f16)0.f,(f16)0.f,(f16)0.f,(f16)0.f,(f16)0.f,(f16)0.f,(f16)0.f};
      *(f16x8*)(z + (size_t)n*EMB + dl) = zz;
    }
    return;
  }
  float acc[8];
#pragma unroll
  for (int k = 0; k < 8; ++k) acc[k] = 0.f;
  int i1 = rs[n+1];
  int i  = rs[n] + half;
  bool v = i < i1;
  int s = 0, pa = 0;
  if (v){ s = csrc[i]; pa = cattr[i]; }
  while (v){
    f16x8 hv = *(const f16x8*)(h + (size_t)s*EMB + dl);
    f16x8 ev = *(const f16x8*)(ebl + ((size_t)pa << 8) + dl);
    int in = i + 2;
    bool vn = in < i1;
    int sn = 0, pan = 0;
    if (vn){ sn = csrc[in]; pan = cattr[in]; }     // overlap with hv/ev latency
#pragma unroll
    for (int k = 0; k < 8; ++k)
      acc[k] += fmaxf((float)hv[k] + (float)ev[k], 0.f);
    i = in; s = sn; pa = pan; v = vn;
  }
#pragma unroll
  for (int k = 0; k < 8; ++k) acc[k] += __shfl_xor(acc[k], 32);
  if (half == 0){
    float ep = 1.0f + epsv[layer];
    f16x8 hv = *(const f16x8*)(h + (size_t)n*EMB + dl);
    f16x8 o;
#pragma unroll
    for (int k = 0; k < 8; ++k) o[k] = (f16)(acc[k] + ep*(float)hv[k]);
    *(f16x8*)(z + (size_t)n*EMB + dl) = o;
  }
}

// A [M x K] f16 row-major, Bt [NCOL x K] f16 row-major (pre-transposed weights).
// C [M x NCOL] f16 pre-BN; column sum/sumsq accumulated via f32 atomics.
template<int K, int NCOL>
__global__ __launch_bounds__(256)
void k_gemm(const f16* __restrict__ A, const f16* __restrict__ Bt,
            f16* __restrict__ C, float* __restrict__ csum, float* __restrict__ csq){
  __shared__ __align__(16) u16 As[128*64];
  __shared__ __align__(16) u16 Bs[128*64];
  const int tid  = threadIdx.x;
  const int lane = tid & 63;
  const int wid  = tid >> 6;
  const int bm0 = blockIdx.x * 128;
  const int bn0 = blockIdx.y * 128;
  const int wm = (wid >> 1) * 64;
  const int wn = (wid & 1) * 64;

  f32x4 acc[4][4];
#pragma unroll
  for (int m = 0; m < 4; ++m)
#pragma unroll
    for (int n = 0; n < 4; ++n) acc[m][n] = (f32x4){0.f,0.f,0.f,0.f};

  for (int kt = 0; kt < K/64; ++kt){
    __syncthreads();
#pragma unroll
    for (int it = 0; it < 4; ++it){
      int tix = tid + it*256;
      int r = tix >> 3;
      int c = tix & 7;
      int sc = c ^ (r & 7);          // pre-swizzled global source, linear LDS dest
      gload16(A  + (size_t)(bm0 + r)*K + kt*64 + sc*8, (char*)As + tix*16);
      gload16(Bt + (size_t)(bn0 + r)*K + kt*64 + sc*8, (char*)Bs + tix*16);
    }
    __syncthreads();
#pragma unroll
    for (int kk = 0; kk < 2; ++kk){
      f16x8 af[4], bfr[4];
#pragma unroll
      for (int m = 0; m < 4; ++m){
        int row = wm + m*16 + (lane & 15);
        int phys = (kk*4 + (lane >> 4)) ^ (row & 7);
        af[m] = *(const f16x8*)((const char*)As + row*128 + phys*16);
      }
#pragma unroll
      for (int n = 0; n < 4; ++n){
        int row = wn + n*16 + (lane & 15);
        int phys = (kk*4 + (lane >> 4)) ^ (row & 7);
        bfr[n] = *(const f16x8*)((const char*)Bs + row*128 + phys*16);
      }
#pragma unroll
      for (int m = 0; m < 4; ++m)
#pragma unroll
        for (int n = 0; n < 4; ++n)
          acc[m][n] = __builtin_amdgcn_mfma_f32_16x16x32_f16(af[m], bfr[n], acc[m][n], 0, 0, 0);
    }
  }

  const int r0 = (lane >> 4) * 4;
  const int cc = lane & 15;
#pragma unroll
  for (int m = 0; m < 4; ++m)
#pragma unroll
    for (int n = 0; n < 4; ++n)
#pragma unroll
      for (int j = 0; j < 4; ++j){
        int row = bm0 + wm + m*16 + r0 + j;
        int col = bn0 + wn + n*16 + cc;
        C[(size_t)row*NCOL + col] = (f16)acc[m][n][j];
      }
#pragma unroll
  for (int n = 0; n < 4; ++n){
    float s = 0.f, q = 0.f;
#pragma unroll
    for (int m = 0; m < 4; ++m)
#pragma unroll
      for (int j = 0; j < 4; ++j){ float v = acc[m][n][j]; s += v; q += v*v; }
    s += __shfl_xor(s, 16); q += __shfl_xor(q, 16);
    s += __shfl_xor(s, 32); q += __shfl_xor(q, 32);
    if (lane < 16){
      atomicAdd(csum + bn0 + wn + n*16 + cc, s);
      atomicAdd(csq  + bn0 + wn + n*16 + cc, q);
    }
  }
}

__global__ void k_finalize(const float* __restrict__ sum, const float* __restrict__ sumsq,
                           const float* __restrict__ g, const float* __restrict__ be,
                           float* __restrict__ scale, float* __restrict__ shift, int nc){
  int c = blockIdx.x * 256 + threadIdx.x;
  if (c >= nc) return;
  float m = sum[c] * (1.0f / NODES);
  float v = sumsq[c] * (1.0f / NODES) - m*m;
  float sc = rsqrtf(v + BNEPS) * g[c];
  scale[c] = sc;
  shift[c] = be[c] - m*sc;
}

__global__ void k_apply1(f16* __restrict__ hid, const float* __restrict__ scale,
                         const float* __restrict__ shift){
  int idx = blockIdx.x * 256 + threadIdx.x;       // 8 elems each, MPAD*512 total
  int row = idx >> 6;
  int c0  = (idx & 63) * 8;
  f16* p = hid + (size_t)row * 512 + c0;
  if (row >= NODES){
    f16x8 zz = {(f16)0.f,(f16)0.f,(f16)0.f,(f16)0.f,(f16)0.f,(f16)0.f,(f16)0.f,(f16)0.f};
    *(f16x8*)p = zz;
    return;
  }
  f16x8 v = *(const f16x8*)p;
  float4 sA = *(const float4*)(scale + c0), sB = *(const float4*)(scale + c0 + 4);
  float4 tA = *(const float4*)(shift + c0), tB = *(const float4*)(shift + c0 + 4);
  f16x8 o;
  o[0] = (f16)fmaxf((float)v[0]*sA.x + tA.x, 0.f);
  o[1] = (f16)fmaxf((float)v[1]*sA.y + tA.y, 0.f);
  o[2] = (f16)fmaxf((float)v[2]*sA.z + tA.z, 0.f);
  o[3] = (f16)fmaxf((float)v[3]*sA.w + tA.w, 0.f);
  o[4] = (f16)fmaxf((float)v[4]*sB.x + tB.x, 0.f);
  o[5] = (f16)fmaxf((float)v[5]*sB.y + tB.y, 0.f);
  o[6] = (f16)fmaxf((float)v[6]*sB.z + tB.z, 0.f);
  o[7] = (f16)fmaxf((float)v[7]*sB.w + tB.w, 0.f);
  *(f16x8*)p = o;
}

__global__ void k_apply2(const f16* __restrict__ zp, const float* __restrict__ scale,
                         const float* __restrict__ shift, f16* __restrict__ hout,
                         float* __restrict__ fout, int dorelu){
  int idx = blockIdx.x * 256 + threadIdx.x;       // 8 elems each, NODES*256 total
  int row = idx >> 5;
  int c0  = (idx & 31) * 8;
  if (row >= NODES) return;
  size_t off = (size_t)row * EMB + c0;
  f16x8 v = *(const f16x8*)(zp + off);
  float4 sA = *(const float4*)(scale + c0), sB = *(const float4*)(scale + c0 + 4);
  float4 tA = *(const float4*)(shift + c0), tB = *(const float4*)(shift + c0 + 4);
  float r0 = (float)v[0]*sA.x + tA.x;
  float r1 = (float)v[1]*sA.y + tA.y;
  float r2 = (float)v[2]*sA.z + tA.z;
  float r3 = (float)v[3]*sA.w + tA.w;
  float r4 = (float)v[4]*sB.x + tB.x;
  float r5 = (float)v[5]*sB.y + tB.y;
  float r6 = (float)v[6]*sB.z + tB.z;
  float r7 = (float)v[7]*sB.w + tB.w;
  if (dorelu){
    r0=fmaxf(r0,0.f); r1=fmaxf(r1,0.f); r2=fmaxf(r2,0.f); r3=fmaxf(r3,0.f);
    r4=fmaxf(r4,0.f); r5=fmaxf(r5,0.f); r6=fmaxf(r6,0.f); r7=fmaxf(r7,0.f);
  }
  if (fout){
    float4 f0 = {r0,r1,r2,r3}, f1 = {r4,r5,r6,r7};
    float* q = fout + off;
    *(float4*)q = f0; *(float4*)(q + 4) = f1;
  } else {
    f16x8 o = {(f16)r0,(f16)r1,(f16)r2,(f16)r3,(f16)r4,(f16)r5,(f16)r6,(f16)r7};
    *(f16x8*)(hout + off) = o;
  }
}

// ---------------- launch ----------------

extern "C" void kernel_launch(void* const* d_in, const int* in_sizes, int n_in,
                              void* d_out, int out_size, void* d_ws, size_t ws_size,
                              hipStream_t stream){
  const int*   x    = (const int*)  d_in[0];
  const int*   ei   = (const int*)  d_in[1];
  const int*   ea   = (const int*)  d_in[2];
  const float* aemb = (const float*)d_in[3];
  const float* bemb = (const float*)d_in[4];
  const float* epsv = (const float*)d_in[5];
  const float* W1   = (const float*)d_in[6];
  const float* g1   = (const float*)d_in[8];
  const float* be1  = (const float*)d_in[9];
  const float* W2   = (const float*)d_in[10];
  const float* g2   = (const float*)d_in[12];
  const float* be2  = (const float*)d_in[13];
  float* out = (float*)d_out;

  char* p = (char*)d_ws;
  auto take = [&](size_t bytes){ char* r = p; p += (bytes + 255) & ~(size_t)255; return r; };
  f16* h      = (f16*)take((size_t)NODES*EMB*2);
  f16* z      = (f16*)take((size_t)MPAD*EMB*2);     // reused as GEMM2 output
  f16* hidden = (f16*)take((size_t)MPAD*512*2);
  f16* W1t    = (f16*)take((size_t)5*512*256*2);
  f16* W2t    = (f16*)take((size_t)5*256*512*2);
  f16* eb     = (f16*)take((size_t)5*216*256*2);
  float* stats= (float*)take((size_t)4*512*4);
  float* csum = stats, *csq = stats + 512, *scale = stats + 1024, *shift = stats + 1536;
  int* counts = (int*)take((size_t)NODES*4);
  int* rs     = (int*)take((size_t)(NODES+1)*4);
  int* fill   = (int*)take((size_t)NODES*4);
  int* bsums  = (int*)take((size_t)SCANB*4);
  int* csrc   = (int*)take((size_t)EDGES*4);
  int* cattr  = (int*)take((size_t)EDGES*4);

  k_w1t<<<2560, 256, 0, stream>>>(W1, W1t);
  k_w2t<<<2560, 256, 0, stream>>>(W2, W2t);
  k_ebond<<<5*216, 64, 0, stream>>>(bemb, eb);
  k_atom<<<12500, 256, 0, stream>>>(x, aemb, h);
  hipMemsetAsync(counts, 0, (size_t)NODES*4, stream);
  k_hist<<<EDGES/256, 256, 0, stream>>>(ei + EDGES, counts);
  k_bsum<<<SCANB, 256, 0, stream>>>(counts, bsums);
  k_bscan<<<1, 256, 0, stream>>>(bsums);
  k_fill<<<SCANB, 256, 0, stream>>>(counts, bsums, rs, fill);
  k_scatter<<<EDGES/256, 256, 0, stream>>>(ei, ei + EDGES, ea, fill, csrc, cattr);

  for (int l = 0; l < 5; ++l){
    k_gather<<<MPAD/4, 256, 0, stream>>>(h, eb + (size_t)l*216*256, rs, csrc, cattr, epsv, l, z);
    hipMemsetAsync(stats, 0, 2*512*4, stream);
    k_gemm<256,512><<<dim3(MPAD/128, 4), 256, 0, stream>>>(z, W1t + (size_t)l*512*256, hidden, csum, csq);
    k_finalize<<<2, 256, 0, stream>>>(csum, csq, g1 + l*512, be1 + l*512, scale, shift, 512);
    k_apply1<<<MPAD*64/256, 256, 0, stream>>>(hidden, scale, shift);
    hipMemsetAsync(stats, 0, 2*512*4, stream);
    k_gemm<512,256><<<dim3(MPAD/128, 2), 256, 0, stream>>>(hidden, W2t + (size_t)l*256*512, z, csum, csq);
    k_finalize<<<1, 256, 0, stream>>>(csum, csq, g2 + l*256, be2 + l*256, scale, shift, 256);
    if (l < 4)
      k_apply2<<<NODES*32/256, 256, 0, stream>>>(z, scale, shift, h, nullptr, 1);
    else
      k_apply2<<<NODES*32/256, 256, 0, stream>>>(z, scale, shift, nullptr, out, 0);
  }
}